// Round 3
// baseline (231.884 us; speedup 1.0000x reference)
//
#include <hip/hip_runtime.h>

// CNN_36644660970295: 16 steps of [wrap-pad, conv3x3 1->2ch, +b1, tanh,
// conv1x1 2->1ch, +b2, relu] on B=32, 512x512 fp32.
// Round 3: fuse 4 steps, "compute-everything" tiles (no region masks),
// cached strip pointers, padded LDS for unconditional edge scalars.

#define NN 512
#define TILE 64
#define HALO 4
#define BUFW 72
#define BUFN (BUFW * BUFW)        // 5184 floats per buffer
#define NSTRIP 18                 // float4 strips per row
#define WORK (70 * NSTRIP)        // 1260 strips per step (rows 1..70)
#define STAGE_N (BUFW * NSTRIP)   // 1296 staging float4s

__device__ __forceinline__ float tanh_fast(float x) {
    // tanh(x) = 1 - 2/(exp(2x)+1); safe at +/-inf
    float e = __expf(2.0f * x);
    return 1.0f - 2.0f * __builtin_amdgcn_rcpf(e + 1.0f);
}

__global__ __launch_bounds__(256) void fused4(
    const float* __restrict__ in, float* __restrict__ out,
    const float* __restrict__ w1, const float* __restrict__ b1,
    const float* __restrict__ w2, const float* __restrict__ b2)
{
    // [4 pad][buf0: 5184][buf1: 5184][80 pad] ; buf0/buf1 16B-aligned
    __shared__ float lds[4 + 2 * BUFN + 80];
    float* buf0 = lds + 4;

    const int tid = threadIdx.x;
    const int wg  = blockIdx.x;
    const int tx  = wg & 7;
    const int ty  = (wg >> 3) & 7;
    const int b   = wg >> 6;
    const float* img = in + (size_t)b * (NN * NN);
    const int base_r = ty * TILE - HALO;
    const int base_c = tx * TILE - HALO;

    // ---- Stage 72x72 tile (wrap halo) as aligned float4s ----
    #pragma unroll
    for (int k = 0; k < 6; ++k) {
        int w = tid + 256 * k;
        if (w < STAGE_N) {
            int row = w / NSTRIP;                 // const-divisor magic mul
            int c4  = (w - row * NSTRIP) << 2;    // 0,4,...,68
            int gr  = (base_r + row) & (NN - 1);
            int gc  = (base_c + c4) & (NN - 1);   // aligned, wrap-safe
            *reinterpret_cast<float4*>(buf0 + row * BUFW + c4) =
                *reinterpret_cast<const float4*>(img + gr * NN + gc);
        }
    }

    // ---- Weights (uniform scalar loads) ----
    float W1[2][3][3];
    #pragma unroll
    for (int ch = 0; ch < 2; ++ch)
        #pragma unroll
        for (int r = 0; r < 3; ++r)
            #pragma unroll
            for (int q = 0; q < 3; ++q)
                W1[ch][r][q] = w1[ch * 9 + r * 3 + q];
    const float B1_0 = b1[0], B1_1 = b1[1];
    const float W2_0 = w2[0], W2_1 = w2[1];
    const float B2   = b2[0];

    // ---- Precompute strip base pointers (reused by all 4 steps) ----
    // strip k handles w = tid+256k -> output (row0+1, c0); sp points at (row0, c0)
    float* sp[5];
    #pragma unroll
    for (int k = 0; k < 5; ++k) {
        int w   = tid + 256 * k;
        int row = w / NSTRIP;                  // 0..69 (output row - 1)
        int c0  = (w - row * NSTRIP) << 2;
        sp[k] = buf0 + row * BUFW + c0;
    }

    __syncthreads();

    // ---- 4 fused steps; compute ALL strips rows 1..70, no masks ----
    #pragma unroll
    for (int s = 0; s < 4; ++s) {
        const int so  = (s & 1) ? BUFN : 0;    // src buffer float-offset
        const int dof = BUFN - so;             // dst buffer float-offset
        #pragma unroll
        for (int k = 0; k < 5; ++k) {
            int w = tid + 256 * k;
            if (w < WORK) {                    // only k==4 partially active
                const float* p = sp[k] + so;
                float4 a0 = *reinterpret_cast<const float4*>(p);
                float4 a1 = *reinterpret_cast<const float4*>(p + BUFW);
                float4 a2 = *reinterpret_cast<const float4*>(p + 2 * BUFW);
                float c0a[6], c1a[6], c2a[6];
                c0a[0] = p[-1];           c1a[0] = p[BUFW - 1];   c2a[0] = p[2 * BUFW - 1];
                c0a[1] = a0.x; c0a[2] = a0.y; c0a[3] = a0.z; c0a[4] = a0.w;
                c1a[1] = a1.x; c1a[2] = a1.y; c1a[3] = a1.z; c1a[4] = a1.w;
                c2a[1] = a2.x; c2a[2] = a2.y; c2a[3] = a2.z; c2a[4] = a2.w;
                c0a[5] = p[4];            c1a[5] = p[BUFW + 4];   c2a[5] = p[2 * BUFW + 4];

                float res[4];
                #pragma unroll
                for (int px = 0; px < 4; ++px) {
                    float acc0 = B1_0, acc1 = B1_1;
                    #pragma unroll
                    for (int q = 0; q < 3; ++q) {
                        acc0 = fmaf(W1[0][0][q], c0a[px + q], acc0);
                        acc1 = fmaf(W1[1][0][q], c0a[px + q], acc1);
                        acc0 = fmaf(W1[0][1][q], c1a[px + q], acc0);
                        acc1 = fmaf(W1[1][1][q], c1a[px + q], acc1);
                        acc0 = fmaf(W1[0][2][q], c2a[px + q], acc0);
                        acc1 = fmaf(W1[1][2][q], c2a[px + q], acc1);
                    }
                    float t0 = tanh_fast(acc0);
                    float t1 = tanh_fast(acc1);
                    float y  = fmaf(W2_0, t0, fmaf(W2_1, t1, B2));
                    res[px] = fmaxf(y, 0.0f);
                }
                *reinterpret_cast<float4*>(sp[k] + dof + BUFW) =
                    make_float4(res[0], res[1], res[2], res[3]);
            }
        }
        __syncthreads();
    }

    // ---- Write out rows 4..67, cols 4..67 of buf0 (1024 float4s) ----
    float* og = out + (size_t)b * (NN * NN);
    #pragma unroll
    for (int k = 0; k < 4; ++k) {
        int w   = tid + 256 * k;
        int rr  = w >> 4;                // 0..63
        int c4  = (w & 15) << 2;         // 0..60
        float4 v = *reinterpret_cast<const float4*>(
            buf0 + (rr + HALO) * BUFW + (c4 + HALO));
        *reinterpret_cast<float4*>(
            og + (size_t)(ty * TILE + rr) * NN + (tx * TILE + c4)) = v;
    }
}

extern "C" void kernel_launch(void* const* d_in, const int* in_sizes, int n_in,
                              void* d_out, int out_size, void* d_ws, size_t ws_size,
                              hipStream_t stream) {
    const float* x  = (const float*)d_in[0];
    const float* w1 = (const float*)d_in[1];
    const float* b1 = (const float*)d_in[2];
    const float* w2 = (const float*)d_in[3];
    const float* b2 = (const float*)d_in[4];

    float* A = (float*)d_ws;    // ping
    float* B = (float*)d_out;   // pong (final group lands here)

    dim3 grid(32 * 8 * 8), block(256);   // 2048 workgroups

    fused4<<<grid, block, 0, stream>>>(x, A, w1, b1, w2, b2);
    fused4<<<grid, block, 0, stream>>>(A, B, w1, b1, w2, b2);
    fused4<<<grid, block, 0, stream>>>(B, A, w1, b1, w2, b2);
    fused4<<<grid, block, 0, stream>>>(A, B, w1, b1, w2, b2);
}